// Round 6
// baseline (433.606 us; speedup 1.0000x reference)
//
#include <hip/hip_runtime.h>
#include <hip/hip_bf16.h>

#define NB 8
#define L_TOT 4096
#define DIM 256
#define HEADS 8
#define HEAD_DIM 32
#define M_TOT 512
// softmax-scale folded with log2(e) so exp(x) == exp2(S)
#define QSCALE (0.17677669529663687f * 1.4426950408889634f)

typedef float f32x4 __attribute__((ext_vector_type(4)));
typedef short bf16x8 __attribute__((ext_vector_type(8)));

union BF8 { bf16x8 v; unsigned u[4]; uint4 u4; };

// RNE packed f32x2 -> bf16x2 (lowers to v_cvt_pk_bf16_f32)
__device__ __forceinline__ unsigned cvt2(float lo, float hi) {
    __hip_bfloat162 h = __float22bfloat162_rn(make_float2(lo, hi));
    union { __hip_bfloat162 h2; unsigned u; } un;
    un.h2 = h;
    return un.u;
}

// ksF frag-linear layout (16x16x32 A-frags), 16384 shorts per bh:
//   (m,c) -> (m>>4)*512 + (m&15)*8 + (c>>3)*128 + (c&7)
// so the A-frag for m-tile t is one ds_read_b128 at t*512 + lane*8 (shorts).
__global__ __launch_bounds__(256) void ksum_kernel(const float* __restrict__ k,
                                                   unsigned short* __restrict__ ks) {
    const int blk = blockIdx.x;          // 1024 = bh(64) x part(16)
    const int bh = blk >> 4, part = blk & 15;
    const int b = bh >> 3, head = bh & 7;
    const float* kb = k + (size_t)b * L_TOT * DIM + head * HEAD_DIM;
    const int c0 = (threadIdx.x & 7) * 4;          // 4-col group
    const int m = part * 32 + (threadIdx.x >> 3);  // [0,512)
    float4 s = make_float4(0.f, 0.f, 0.f, 0.f);
#pragma unroll
    for (int hq = 0; hq < 8; ++hq) {
        const float4 f = *(const float4*)(kb + (size_t)(hq * 512 + m) * DIM + c0);
        s.x += f.x; s.y += f.y; s.z += f.z; s.w += f.w;
    }
    uint2 o;
    o.x = cvt2(s.x, s.y);
    o.y = cvt2(s.z, s.w);
    const size_t off = (size_t)bh * 16384 + (m >> 4) * 512 + (m & 15) * 8 +
                       (c0 >> 3) * 128 + (c0 & 7);
    *(uint2*)(ks + off) = o;
}

// Block = (bh, h), 1024 threads (16 waves), 2 blocks/CU -> 32 waves/CU.
// Wave owns 16 q-rows per pass (2 passes). 16x16x32 MFMA, K=32=head_dim:
// S = one MFMA; P A-frag = cvt_pk words directly (pi-permuted V layout,
// no cross-lane ops); O = 2 c-tiles.
template <bool USE_WS>
__global__ __launch_bounds__(1024, 8) void attn_kernel(const float* __restrict__ q,
                                                       const float* __restrict__ kg,
                                                       const float* __restrict__ v,
                                                       const unsigned short* __restrict__ ks,
                                                       float* __restrict__ out) {
    // shorts: ksF[16384] | vF[16384] | inv[16 waves][16] floats
    __shared__ __align__(16) unsigned short smem[32768 + 512];
    unsigned short* ksF = smem;
    unsigned short* vF = smem + 16384;
    float* invAll = (float*)(smem + 32768);

    const int tid = threadIdx.x;
    const int wave = tid >> 6;
    const int lane = tid & 63;
    const int l15 = lane & 15;
    const int g = lane >> 4;           // k-octet group

    // XCD-aware swizzle (512 % 8 == 0 -> bijective)
    const int bid = blockIdx.x;
    const int wk = (bid & 7) * 64 + (bid >> 3);
    const int bh = wk >> 3, h = wk & 7;
    const int b = bh >> 3, head = bh & 7;

    // ---- stage ksF ----
    if (USE_WS) {
        const uint4* ksrc4 = (const uint4*)(ks + (size_t)bh * 16384);
        uint4* kdst4 = (uint4*)ksF;
        kdst4[tid] = ksrc4[tid];
        kdst4[1024 + tid] = ksrc4[1024 + tid];
    } else {
        const float* kb = kg + (size_t)b * L_TOT * DIM + head * HEAD_DIM;
#pragma unroll
        for (int it = 0; it < 4; ++it) {
            const int idx = it * 1024 + tid;           // [0,4096)
            const int m = idx >> 3, c0 = (idx & 7) * 4;
            float4 s = make_float4(0.f, 0.f, 0.f, 0.f);
#pragma unroll
            for (int hq = 0; hq < 8; ++hq) {
                const float4 f = *(const float4*)(kb + (size_t)(hq * 512 + m) * DIM + c0);
                s.x += f.x; s.y += f.y; s.z += f.z; s.w += f.w;
            }
            uint2 o; o.x = cvt2(s.x, s.y); o.y = cvt2(s.z, s.w);
            *(uint2*)(ksF + (m >> 4) * 512 + (m & 15) * 8 + (c0 >> 3) * 128 + (c0 & 7)) = o;
        }
    }

    // ---- stage vF with pi-permuted m order ----
    // B-frag slot (g,j) of chunk ch, c-tile u must hold V[32ch + pi(8g+j)][16u + (lane&15)]
    // with pi(8g+j) = (j<4) ? 4g+j : 16 + 4g + (j-4).
    // Inverse: (m,c): ch=m>>5, mm=m&31, g=(mm&15)>>2, j=(mm&3)+(mm>=16?4:0);
    //   off = (2ch + (c>>4))*512 + (16g + (c&15))*8 + j
    const float* vbase = v + ((size_t)b * L_TOT + h * M_TOT) * DIM + head * HEAD_DIM;
#pragma unroll
    for (int it = 0; it < 4; ++it) {
        const int idx = it * 1024 + tid;     // [0, 4096)
        const int m = idx >> 3, c0 = (idx & 7) * 4;
        const float4 f = *(const float4*)(vbase + (size_t)m * DIM + c0);
        const unsigned w0 = cvt2(f.x, f.y), w1 = cvt2(f.z, f.w);
        const int mm = m & 31;
        const int vg = (mm & 15) >> 2;
        const int vj = (mm & 3) + (mm >= 16 ? 4 : 0);
        unsigned short* bp = vF + (2 * (m >> 5) + (c0 >> 4)) * 512 + vj +
                             (16 * vg + (c0 & 15)) * 8;
        bp[0]  = (unsigned short)w0;
        bp[8]  = (unsigned short)(w0 >> 16);
        bp[16] = (unsigned short)w1;
        bp[24] = (unsigned short)(w1 >> 16);
    }
    __syncthreads();

    const unsigned short* ksW = ksF + lane * 8;
    const unsigned short* vfW = vF + lane * 8;
    float* invW = invAll + wave * 16;
    const float* qbase = q + (size_t)b * L_TOT * DIM + head * HEAD_DIM;

    for (int gi = 0; gi < 2; ++gi) {
        const int G = wave * 2 + gi;          // [0,32): 8 windows x 4 row-quads
        const int wcol = G >> 2, n0 = (G & 3) * 16;

        // q B-frag: col = qrow = l15, k-slot (g,j) = c = 8g+j
        const int Lq = (h * 8 + (n0 >> 3) + (l15 >> 3)) * 64 + wcol * 8 + (lane & 7);
        const float* qp = qbase + (size_t)Lq * DIM + 8 * g;
        BF8 qf;
        {
            const float4 f0 = *(const float4*)(qp);
            const float4 f1 = *(const float4*)(qp + 4);
            qf.u[0] = cvt2(f0.x * QSCALE, f0.y * QSCALE);
            qf.u[1] = cvt2(f0.z * QSCALE, f0.w * QSCALE);
            qf.u[2] = cvt2(f1.x * QSCALE, f1.y * QSCALE);
            qf.u[3] = cvt2(f1.z * QSCALE, f1.w * QSCALE);
        }

        f32x4 O0 = {0.f, 0.f, 0.f, 0.f};
        f32x4 O1 = {0.f, 0.f, 0.f, 0.f};
        const f32x4 Z = {0.f, 0.f, 0.f, 0.f};
        float lsum = 0.f;

#pragma unroll
        for (int ch = 0; ch < 16; ++ch) {
            BF8 A0, A1, VB0, VB1;
            A0.u4  = *(const uint4*)(ksW + ch * 1024);        // m-tile 2ch
            A1.u4  = *(const uint4*)(ksW + ch * 1024 + 512);  // m-tile 2ch+1
            VB0.u4 = *(const uint4*)(vfW + ch * 1024);        // c-tile 0
            VB1.u4 = *(const uint4*)(vfW + ch * 1024 + 512);  // c-tile 1

            // S: col = qrow = l15, row(reg r) = m-in-tile = 4g + r
            f32x4 S0 = __builtin_amdgcn_mfma_f32_16x16x32_bf16(A0.v, qf.v, Z, 0, 0, 0);
            f32x4 S1 = __builtin_amdgcn_mfma_f32_16x16x32_bf16(A1.v, qf.v, Z, 0, 0, 0);

            const float p00 = __builtin_amdgcn_exp2f(S0[0]);
            const float p01 = __builtin_amdgcn_exp2f(S0[1]);
            const float p02 = __builtin_amdgcn_exp2f(S0[2]);
            const float p03 = __builtin_amdgcn_exp2f(S0[3]);
            const float p10 = __builtin_amdgcn_exp2f(S1[0]);
            const float p11 = __builtin_amdgcn_exp2f(S1[1]);
            const float p12 = __builtin_amdgcn_exp2f(S1[2]);
            const float p13 = __builtin_amdgcn_exp2f(S1[3]);
            lsum += ((p00 + p01) + (p02 + p03)) + ((p10 + p11) + (p12 + p13));

            // P A-frag: row = qrow = l15 (lane-local), slots in pi order -> own words
            BF8 PA;
            PA.u[0] = cvt2(p00, p01);
            PA.u[1] = cvt2(p02, p03);
            PA.u[2] = cvt2(p10, p11);
            PA.u[3] = cvt2(p12, p13);
            O0 = __builtin_amdgcn_mfma_f32_16x16x32_bf16(PA.v, VB0.v, O0, 0, 0, 0);
            O1 = __builtin_amdgcn_mfma_f32_16x16x32_bf16(PA.v, VB1.v, O1, 0, 0, 0);
        }

        // lsum currently covers m-subset {4g+r}+{16+4g+r} per lane; reduce over g
        lsum += __shfl_xor(lsum, 16, 64);
        lsum += __shfl_xor(lsum, 32, 64);
        const float inv = __builtin_amdgcn_rcpf(lsum);
        if (lane < 16) invW[l15] = inv;      // inv for qrow = l15
        const float4 iv = *(const float4*)(invW + 4 * g);  // qrows 4g..4g+3

        // O: col = c = 16u + l15, row(r) = qrow = 4g + r
        const int rowL = (h * 8 + (n0 >> 3) + (g >> 1)) * 64 + wcol * 8 + ((4 * g) & 7);
        float* ob = out + ((size_t)b * L_TOT + rowL) * DIM + head * HEAD_DIM + l15;
        ob[0 * DIM]      = O0[0] * iv.x;  ob[0 * DIM + 16] = O1[0] * iv.x;
        ob[1 * DIM]      = O0[1] * iv.y;  ob[1 * DIM + 16] = O1[1] * iv.y;
        ob[2 * DIM]      = O0[2] * iv.z;  ob[2 * DIM + 16] = O1[2] * iv.z;
        ob[3 * DIM]      = O0[3] * iv.w;  ob[3 * DIM + 16] = O1[3] * iv.w;
    }
}

extern "C" void kernel_launch(void* const* d_in, const int* in_sizes, int n_in,
                              void* d_out, int out_size, void* d_ws, size_t ws_size,
                              hipStream_t stream) {
    const float* qkv = (const float*)d_in[0];
    const float* q = qkv;
    const float* k = qkv + (size_t)NB * L_TOT * DIM;
    const float* v = qkv + (size_t)2 * NB * L_TOT * DIM;
    float* out = (float*)d_out;
    const size_t ks_bytes = (size_t)NB * HEADS * M_TOT * HEAD_DIM * 2;  // 2 MB
    if (ws_size >= ks_bytes) {
        unsigned short* ks = (unsigned short*)d_ws;
        ksum_kernel<<<dim3(1024), dim3(256), 0, stream>>>(k, ks);
        attn_kernel<true><<<dim3(512), dim3(1024), 0, stream>>>(q, k, v, ks, out);
    } else {
        attn_kernel<false><<<dim3(512), dim3(1024), 0, stream>>>(q, k, v, nullptr, out);
    }
}